// Round 8
// baseline (587.905 us; speedup 1.0000x reference)
//
#include <hip/hip_runtime.h>
#include <cstdint>
#include <cstddef>

// VectorQuantizer: x (16,128,4096) f32, W (1024,128) f32
// out = [quantized_st 8388608 | indices 65536 (as float) | loss 1]
//
// R8: stop fighting the register allocator (R6 spilled xr, R7 rematerialized
// it from global). New placement:
//   - x rows in LDS (64 rows x 132-float padded stride, 16B aligned; b128
//     reads start at banks 4*(lane)+d mod 32 -> tile all 32 banks -> BW floor)
//   - W on the scalar pipe (uniform s_load_dwordx4, proven in R6/R7)
//   - 8 interleaved code-chains per group -> one x read serves 8 codes
//     (8x less LDS traffic than R2's W-in-LDS structure)
// Bit-exact numpy-f32 contract unchanged (absmax 0 in R2/R6/R7): strict
// d-ascending FMA chain per code, fl(fl(a+b)-2c), ascending strict-< argmin.

#define BB 16
#define DD 128
#define TT 4096
#define KK 1024
#define NROW 65536
#define QSIZE 8388608
#define IDX_BASE QSIZE
#define LOSS_IDX (QSIZE + NROW)
#define COMMIT 0.25f
#define TPB 256
#define RPB 64            // rows per block (4 waves, each scans 256 codes)
#define SEG 4
#define CPS 256
#define XS 132            // padded row stride in floats (16B-aligned)

// optimization barrier: keep value as-is, block fp contraction across it
__device__ __forceinline__ float fb(float v) {
    asm volatile("" : "+v"(v));
    return v;
}

// Kernel 1: b_k = numpy-pairwise sum of fl(W[k][d]^2); zero the loss slot.
__global__ void vq_prep(const float* __restrict__ W, float* __restrict__ wsq,
                        float* __restrict__ d_out) {
    int k = blockIdx.x * blockDim.x + threadIdx.x;
    if (k == 0 && blockIdx.x == 0) d_out[LOSS_IDX] = 0.f;
    if (k < KK) {
        const float* Wr = W + (size_t)k * DD;
        float rr[8];
        #pragma unroll
        for (int j = 0; j < 8; ++j) {
            float w = Wr[j];
            float pp = w * w;
            pp = fb(pp);
            rr[j] = pp;
        }
        #pragma unroll
        for (int i = 8; i <= 120; i += 8) {
            #pragma unroll
            for (int j = 0; j < 8; ++j) {
                float w = Wr[i + j];
                float pp = w * w;
                pp = fb(pp);
                rr[j] += pp;
            }
        }
        wsq[k] = ((rr[0] + rr[1]) + (rr[2] + rr[3])) + ((rr[4] + rr[5]) + (rr[6] + rr[7]));
    }
}

__global__ __launch_bounds__(TPB, 4)
void vq_main(const float* __restrict__ x, const float* __restrict__ W,
             const float* __restrict__ wsq, float* __restrict__ d_out) {
    const int tid   = threadIdx.x;
    const int row_l = tid & (RPB - 1);                        // = lane
    const int q = __builtin_amdgcn_readfirstlane(tid >> 6);   // wave-uniform segment
    const int b  = blockIdx.x >> 6;        // 64 blocks per batch image
    const int t0 = (blockIdx.x & 63) << 6;
    const int t  = t0 + row_l;
    const int r  = (blockIdx.x << 6) + row_l;

    __shared__ __align__(16) float xs[RPB * XS];   // 33.8 KB
    __shared__ float ms[SEG][RPB];
    __shared__ int   mk[SEG][RPB];
    __shared__ int   fk[RPB];
    __shared__ float wred[4];

    // ---- stage x rows into LDS (coalesced global reads) ----
    const float* xg = x + (size_t)b * DD * TT + t0;
    #pragma unroll
    for (int ch = 0; ch < 32; ++ch) {
        int idx = ch * TPB + tid;          // 0..8191
        int d  = idx >> 6;
        int tl = idx & 63;
        xs[tl * XS + d] = xg[(size_t)d * TT + tl];
    }
    __syncthreads();

    const float* __restrict__ xrow = &xs[row_l * XS];

    // ---- a_r: numpy pairwise of fl(x_d^2) (order-exact) ----
    float rr[8];
    {
        float4 f0 = *(const float4*)(xrow + 0);
        float4 f1 = *(const float4*)(xrow + 4);
        float p;
        p = f0.x * f0.x; p = fb(p); rr[0] = p;
        p = f0.y * f0.y; p = fb(p); rr[1] = p;
        p = f0.z * f0.z; p = fb(p); rr[2] = p;
        p = f0.w * f0.w; p = fb(p); rr[3] = p;
        p = f1.x * f1.x; p = fb(p); rr[4] = p;
        p = f1.y * f1.y; p = fb(p); rr[5] = p;
        p = f1.z * f1.z; p = fb(p); rr[6] = p;
        p = f1.w * f1.w; p = fb(p); rr[7] = p;
    }
    #pragma unroll
    for (int i = 8; i <= 120; i += 8) {
        float4 f0 = *(const float4*)(xrow + i);
        float4 f1 = *(const float4*)(xrow + i + 4);
        float p;
        p = f0.x * f0.x; p = fb(p); rr[0] += p;
        p = f0.y * f0.y; p = fb(p); rr[1] += p;
        p = f0.z * f0.z; p = fb(p); rr[2] += p;
        p = f0.w * f0.w; p = fb(p); rr[3] += p;
        p = f1.x * f1.x; p = fb(p); rr[4] += p;
        p = f1.y * f1.y; p = fb(p); rr[5] += p;
        p = f1.z * f1.z; p = fb(p); rr[6] += p;
        p = f1.w * f1.w; p = fb(p); rr[7] += p;
    }
    const float a = ((rr[0] + rr[1]) + (rr[2] + rr[3])) + ((rr[4] + rr[5]) + (rr[6] + rr[7]));

    // ---- scan codes [q*256, (q+1)*256): 8 interleaved seq-FMA chains ----
    float best = 3.4e38f;
    int bk = 0;
    const int c0 = q * CPS;

#define CODE_CHAIN(j) { \
        float4 w = *(const float4*)(Wg + (j) * DD + dc); \
        s##j = __builtin_fmaf(xv.x, w.x, s##j); \
        s##j = __builtin_fmaf(xv.y, w.y, s##j); \
        s##j = __builtin_fmaf(xv.z, w.z, s##j); \
        s##j = __builtin_fmaf(xv.w, w.w, s##j); }

#define CMP(j) { \
        float tw = s##j + s##j; \
        float t1 = a + wsq[c + (j)]; \
        float dist = t1 - tw; \
        if (dist < best) { best = dist; bk = c + (j); } }

    #pragma unroll 1
    for (int g = 0; g < 32; ++g) {
        const int c = c0 + g * 8;                              // uniform
        const float* __restrict__ Wg = W + (size_t)c * DD;     // uniform base
        float s0 = 0.f, s1 = 0.f, s2 = 0.f, s3 = 0.f;
        float s4 = 0.f, s5 = 0.f, s6 = 0.f, s7 = 0.f;
        #pragma unroll
        for (int dc = 0; dc < DD; dc += 4) {
            float4 xv = *(const float4*)(xrow + dc);           // LDS b128
            CODE_CHAIN(0) CODE_CHAIN(1) CODE_CHAIN(2) CODE_CHAIN(3)
            CODE_CHAIN(4) CODE_CHAIN(5) CODE_CHAIN(6) CODE_CHAIN(7)
        }
        // ascending code order, strict < => numpy first-occurrence argmin
        CMP(0) CMP(1) CMP(2) CMP(3) CMP(4) CMP(5) CMP(6) CMP(7)
    }
#undef CODE_CHAIN
#undef CMP

    // ---- merge 4 segments (ascending; strict < keeps first occurrence) ----
    ms[q][row_l] = best; mk[q][row_l] = bk;
    __syncthreads();
    if (q == 0) {
        float m = ms[0][row_l]; int kf = mk[0][row_l];
        #pragma unroll
        for (int s = 1; s < SEG; ++s) {
            float v = ms[s][row_l];
            if (v < m) { m = v; kf = mk[s][row_l]; }
        }
        fk[row_l] = kf;
        d_out[IDX_BASE + r] = (float)kf;
    }
    __syncthreads();
    const int kf = fk[row_l];

    // ---- epilogue: quantized_st = fl(x + fl(q - x)); loss partial ----
    // segment q handles d in [q*32, q*32+32); x from LDS (runtime idx OK)
    const float* Wk = W + (size_t)kf * DD;
    float* outq = d_out + (size_t)b * DD * TT + t;
    float acc = 0.f;
    const int dbase = q * 32;
    #pragma unroll
    for (int dq = 0; dq < 8; ++dq) {
        const int d0 = dbase + dq * 4;
        float4 q4 = *(const float4*)(Wk + d0);
        float4 xv = *(const float4*)(xrow + d0);
        { float dlt = q4.x - xv.x; outq[(size_t)(d0 + 0) * TT] = xv.x + dlt; acc = fmaf(dlt, dlt, acc); }
        { float dlt = q4.y - xv.y; outq[(size_t)(d0 + 1) * TT] = xv.y + dlt; acc = fmaf(dlt, dlt, acc); }
        { float dlt = q4.z - xv.z; outq[(size_t)(d0 + 2) * TT] = xv.z + dlt; acc = fmaf(dlt, dlt, acc); }
        { float dlt = q4.w - xv.w; outq[(size_t)(d0 + 3) * TT] = xv.w + dlt; acc = fmaf(dlt, dlt, acc); }
    }

    // block-reduce loss partial -> one atomic per block
    #pragma unroll
    for (int off = 32; off > 0; off >>= 1) acc += __shfl_down(acc, off, 64);
    const int wid = tid >> 6;
    if ((tid & 63) == 0) wred[wid] = acc;
    __syncthreads();
    if (tid == 0) {
        float ssum = (wred[0] + wred[1]) + (wred[2] + wred[3]);
        atomicAdd(&d_out[LOSS_IDX], ssum * (COMMIT / (float)QSIZE));
    }
}

extern "C" void kernel_launch(void* const* d_in, const int* in_sizes, int n_in,
                              void* d_out, int out_size, void* d_ws, size_t ws_size,
                              hipStream_t stream) {
    const float* x = (const float*)d_in[0];
    const float* W = (const float*)d_in[1];
    float* out = (float*)d_out;
    float* wsq = (float*)d_ws;   // 1024 floats of scratch

    vq_prep<<<4, 256, 0, stream>>>(W, wsq, out);
    vq_main<<<NROW / RPB, TPB, 0, stream>>>(x, W, wsq, out);
}

// Round 11
// 277.253 us; speedup vs baseline: 2.1205x; 2.1205x over previous
//
#include <hip/hip_runtime.h>
#include <cstdint>
#include <cstddef>

// VectorQuantizer: x (16,128,4096) f32, W (1024,128) f32
// out = [quantized_st 8388608 | indices 65536 (as float) | loss 1]
//
// R11 (= R9 resubmitted; repeated infra timeouts): MFMA approx scan + exact refine.
//  - f16 hi/lo split of x and of W*8192 (pow2 scale, exact); 3 MFMA passes
//    (wh*xh, wl*xh, wh*xl) approximate c = x.w with |err| <~ 3e-6.
//  - pass1: per-row approx min m1.  pass2: recompute, collect candidates
//    dist <= m1 + (5e-7*m1 + 1e-5)  (margin >= 2*max shift incl ulp(128)
//    quantization -> provably contains the exact argmin).
//  - refine: exact fp32 sequential chain (R2-proven, bit-matches numpy/BLAS)
//    per candidate; winner via u64 key (bits(dist)<<10 | idx) atomicMin ->
//    exact first-occurrence argmin semantics.
//  - epilogue: quantized_st = fl(x + fl(q-x)), loss partials, one atomic.
// Robustness note: A and B frags share the k=(lane/16)*8+j convention, so
// any HW k-permutation cancels in the dot product; only the C/D mapping
// (col=lane&15 -> x-row, row=(lane>>4)*4+reg -> code) must be exact.

#define DD 128
#define TT 4096
#define KK 1024
#define QSIZE 8388608
#define IDX_BASE QSIZE
#define LOSS_IDX (QSIZE + 65536)
#define COMMIT 0.25f
#define TPB 256
#define ROWS 64
#define WSCALE 8192.0f
#define NINV2S -0.000244140625f   // -2^-12 : dist = fma(acc, -2^-12, a+b)
#define CANDCAP 1024

typedef _Float16 half8 __attribute__((ext_vector_type(8)));
typedef float f32x4 __attribute__((ext_vector_type(4)));
typedef unsigned long long u64;

__device__ __forceinline__ float fb(float v) { asm volatile("" : "+v"(v)); return v; }

// ---- prep: exact ||w||^2 (numpy pairwise) + f16 hi/lo planes of W*8192 ----
// plane layout (A-frag for 16x16x32: row=lane%16 -> code, k=(lane/16)*8+j -> d):
//   plane[((m*4 + kstep)*2 + pl)*64 + (kg*16 + row)]*8 + j   (u16 units)
__global__ void vq_prep(const float* __restrict__ W, float* __restrict__ ws,
                        float* __restrict__ d_out) {
    const int g = blockIdx.x * 256 + threadIdx.x;   // 64 blocks -> 16384 threads
    if (g == 0) d_out[LOSS_IDX] = 0.f;
    const int k = g >> 4, c = g & 15;
    if (k >= KK) return;
    const float* Wr = W + (size_t)k * DD;
    if (c == 0) {
        float rr[8];
        #pragma unroll
        for (int j = 0; j < 8; ++j) { float p = Wr[j] * Wr[j]; p = fb(p); rr[j] = p; }
        #pragma unroll
        for (int i = 8; i <= 120; i += 8) {
            #pragma unroll
            for (int j = 0; j < 8; ++j) { float p = Wr[i + j] * Wr[i + j]; p = fb(p); rr[j] += p; }
        }
        ws[k] = ((rr[0] + rr[1]) + (rr[2] + rr[3])) + ((rr[4] + rr[5]) + (rr[6] + rr[7]));
    }
    const int kstep = c >> 2, kg = c & 3, d0 = kstep * 32 + kg * 8;
    half8 hh, hl;
    #pragma unroll
    for (int j = 0; j < 8; ++j) {
        float s = Wr[d0 + j] * WSCALE;       // exact (pow2)
        _Float16 h = (_Float16)s;
        hh[j] = h;
        hl[j] = (_Float16)(s - (float)h);
    }
    unsigned short* plane = (unsigned short*)(ws + KK);
    const int m = k >> 4, row = k & 15, lane = kg * 16 + row;
    *(half8*)(plane + ((((size_t)m * 4 + kstep) * 2 + 0) * 64 + lane) * 8) = hh;
    *(half8*)(plane + ((((size_t)m * 4 + kstep) * 2 + 1) * 64 + lane) * 8) = hl;
}

// one 16(codes)x16(rows) tile x K=128, 3 planes, 2 row-tiles -> acc0/acc1
__device__ __forceinline__ void mfma_tile(int mg, int lane,
        const unsigned short* __restrict__ plane, const half8 (&bf)[2][4][2],
        f32x4& acc0, f32x4& acc1) {
    half8 af[4][2];
    #pragma unroll
    for (int k = 0; k < 4; ++k)
        #pragma unroll
        for (int pl = 0; pl < 2; ++pl)
            af[k][pl] = *(const half8*)(plane + ((((size_t)mg * 4 + k) * 2 + pl) * 64 + lane) * 8);
    acc0 = (f32x4){0.f, 0.f, 0.f, 0.f};
    acc1 = (f32x4){0.f, 0.f, 0.f, 0.f};
    #pragma unroll
    for (int k = 0; k < 4; ++k) {
        acc0 = __builtin_amdgcn_mfma_f32_16x16x32_f16(af[k][0], bf[0][k][0], acc0, 0, 0, 0);
        acc1 = __builtin_amdgcn_mfma_f32_16x16x32_f16(af[k][0], bf[1][k][0], acc1, 0, 0, 0);
        acc0 = __builtin_amdgcn_mfma_f32_16x16x32_f16(af[k][1], bf[0][k][0], acc0, 0, 0, 0);
        acc1 = __builtin_amdgcn_mfma_f32_16x16x32_f16(af[k][1], bf[1][k][0], acc1, 0, 0, 0);
        acc0 = __builtin_amdgcn_mfma_f32_16x16x32_f16(af[k][0], bf[0][k][1], acc0, 0, 0, 0);
        acc1 = __builtin_amdgcn_mfma_f32_16x16x32_f16(af[k][0], bf[1][k][1], acc1, 0, 0, 0);
    }
}

__global__ __launch_bounds__(TPB, 3)
void vq_main(const float* __restrict__ x, const float* __restrict__ W,
             const float* __restrict__ ws, float* __restrict__ d_out) {
    const int tid  = threadIdx.x;
    const int lane = tid & 63;
    const int w    = __builtin_amdgcn_readfirstlane(tid >> 6);
    const int blk  = blockIdx.x;
    const int b    = blk >> 6;               // 64 blocks per batch image
    const int t0   = (blk & 63) * 64;
    const float* xg = x + (size_t)b * DD * TT + t0;

    __shared__ unsigned short xpl[16384];    // 32 KB: x f16 hi/lo planes (B-frag layout)
    __shared__ float bbuf[KK];               // exact ||w||^2
    __shared__ float aLDS[ROWS];             // exact ||x||^2 per row
    __shared__ float m1h[2][ROWS];
    __shared__ float m1row[ROWS];
    __shared__ int   cand[CANDCAP];
    __shared__ int   candN;
    __shared__ u64   rowkey[ROWS];
    __shared__ float wred[4];

    if (tid == 0) candN = 0;
    if (tid < ROWS) rowkey[tid] = ~0ULL;

    // ---- stage x planes: B-frag layout (col=lane%16 -> row-in-tile, kg=lane/16) ----
    #pragma unroll
    for (int p = 0; p < 4; ++p) {
        const int combo = p * 4 + w;
        const int kstep = combo >> 2, kg = combo & 3;
        const int t = tid & 63;
        half8 hh, hl;
        #pragma unroll
        for (int j = 0; j < 8; ++j) {
            float v = xg[(size_t)(kstep * 32 + kg * 8 + j) * TT + t];
            _Float16 h = (_Float16)v;
            hh[j] = h;
            hl[j] = (_Float16)(v - (float)h);
        }
        const int n = t >> 4, col = t & 15;
        *(half8*)(xpl + (((n * 4 + kstep) * 2 + 0) * 64 + (col * 4 + kg)) * 8) = hh;
        *(half8*)(xpl + (((n * 4 + kstep) * 2 + 1) * 64 + (col * 4 + kg)) * 8) = hl;
    }
    #pragma unroll
    for (int s = 0; s < 4; ++s) bbuf[tid + 256 * s] = ws[tid + 256 * s];
    // exact a_r (numpy pairwise of fl(x^2)), one thread per row
    if (tid < ROWS) {
        const float* xb = xg + tid;
        float rr[8];
        #pragma unroll
        for (int j = 0; j < 8; ++j) { float v = xb[(size_t)j * TT]; float p = v * v; p = fb(p); rr[j] = p; }
        #pragma unroll
        for (int i = 8; i <= 120; i += 8) {
            #pragma unroll
            for (int j = 0; j < 8; ++j) { float v = xb[(size_t)(i + j) * TT]; float p = v * v; p = fb(p); rr[j] += p; }
        }
        aLDS[tid] = ((rr[0] + rr[1]) + (rr[2] + rr[3])) + ((rr[4] + rr[5]) + (rr[6] + rr[7]));
    }
    __syncthreads();

    // ---- per-wave role: rhalf = rows 0-31 / 32-63, chalf = codes 0-511 / 512-1023 ----
    const int rhalf = w >> 1, chalf = w & 1;
    const unsigned short* plane = (const unsigned short*)(ws + KK);
    half8 bf[2][4][2];
    {
        const int slot = (lane & 15) * 4 + (lane >> 4);
        #pragma unroll
        for (int n2 = 0; n2 < 2; ++n2)
            #pragma unroll
            for (int k = 0; k < 4; ++k)
                #pragma unroll
                for (int pl = 0; pl < 2; ++pl)
                    bf[n2][k][pl] = *(const half8*)(xpl + ((((rhalf * 2 + n2) * 4 + k) * 2 + pl) * 64 + slot) * 8);
    }
    const int col0 = rhalf * 32 + (lane & 15);
    const int col1 = col0 + 16;
    const float a0 = aLDS[col0], a1 = aLDS[col1];

    // ---- pass 1: approx min per row ----
    float m1a = 3.4e38f, m1b = 3.4e38f;
    #pragma unroll 1
    for (int m = 0; m < 32; ++m) {
        const int mg = chalf * 32 + m;
        const int cb = mg * 16 + (lane >> 4) * 4;
        f32x4 b4 = *(const f32x4*)(ws + cb);
        f32x4 acc0, acc1;
        mfma_tile(mg, lane, plane, bf, acc0, acc1);
#define SCORE1(r) { \
        float d0v = __builtin_fmaf(acc0[r], NINV2S, a0 + b4[r]); \
        float d1v = __builtin_fmaf(acc1[r], NINV2S, a1 + b4[r]); \
        m1a = fminf(m1a, d0v); m1b = fminf(m1b, d1v); }
        SCORE1(0) SCORE1(1) SCORE1(2) SCORE1(3)
#undef SCORE1
    }
    #pragma unroll
    for (int off = 16; off <= 32; off <<= 1) {
        m1a = fminf(m1a, __shfl_xor(m1a, off, 64));
        m1b = fminf(m1b, __shfl_xor(m1b, off, 64));
    }
    if (lane < 16) { m1h[chalf][col0] = m1a; m1h[chalf][col1] = m1b; }
    __syncthreads();
    if (tid < ROWS) m1row[tid] = fminf(m1h[0][tid], m1h[1][tid]);
    __syncthreads();

    // ---- pass 2: collect candidates within provable margin of m1 ----
    const float mm0 = m1row[col0], mm1 = m1row[col1];
    const float thr0 = mm0 + __builtin_fmaf(mm0, 5e-7f, 1e-5f);
    const float thr1 = mm1 + __builtin_fmaf(mm1, 5e-7f, 1e-5f);
    #pragma unroll 1
    for (int m = 0; m < 32; ++m) {
        const int mg = chalf * 32 + m;
        const int cb = mg * 16 + (lane >> 4) * 4;
        f32x4 b4 = *(const f32x4*)(ws + cb);
        f32x4 acc0, acc1;
        mfma_tile(mg, lane, plane, bf, acc0, acc1);
#define SCORE2(r) { \
        float d0v = __builtin_fmaf(acc0[r], NINV2S, a0 + b4[r]); \
        float d1v = __builtin_fmaf(acc1[r], NINV2S, a1 + b4[r]); \
        if (d0v <= thr0) { int s_ = atomicAdd(&candN, 1); if (s_ < CANDCAP) cand[s_] = (col0 << 10) | (cb + (r)); } \
        if (d1v <= thr1) { int s_ = atomicAdd(&candN, 1); if (s_ < CANDCAP) cand[s_] = (col1 << 10) | (cb + (r)); } }
        SCORE2(0) SCORE2(1) SCORE2(2) SCORE2(3)
#undef SCORE2
    }
    __syncthreads();

    // ---- refine: exact fp32 sequential chain (bit-matches numpy ref) ----
    const int nc = min(candN, CANDCAP);
    for (int i = tid; i < nc; i += TPB) {
        const int pk = cand[i];
        const int rowb = pk >> 10, cid = pk & 1023;
        const float* Wc = W + (size_t)cid * DD;
        const float* xr = xg + rowb;
        float s = 0.f;
        #pragma unroll 4
        for (int dq = 0; dq < 32; ++dq) {
            f32x4 w4 = *(const f32x4*)(Wc + dq * 4);
            s = __builtin_fmaf(xr[(size_t)(dq * 4 + 0) * TT], w4[0], s);
            s = __builtin_fmaf(xr[(size_t)(dq * 4 + 1) * TT], w4[1], s);
            s = __builtin_fmaf(xr[(size_t)(dq * 4 + 2) * TT], w4[2], s);
            s = __builtin_fmaf(xr[(size_t)(dq * 4 + 3) * TT], w4[3], s);
        }
        float tw = s + s;
        float t1 = aLDS[rowb] + bbuf[cid];
        float dist = t1 - tw;
        u64 key = ((u64)__float_as_uint(dist) << 10) | (unsigned)cid;
        atomicMin(&rowkey[rowb], key);
    }
    __syncthreads();

    if (tid < ROWS) d_out[IDX_BASE + blk * ROWS + tid] = (float)(int)(rowkey[tid] & 1023);
    __syncthreads();

    // ---- epilogue: quantized_st = fl(x + fl(q - x)); loss ----
    const int kf = (int)(rowkey[lane] & 1023);
    const float* Wk = W + (size_t)kf * DD + w * 32;
    const float* xe = xg + lane;
    float* outq = d_out + (size_t)b * DD * TT + t0 + lane;
    float acc = 0.f;
    #pragma unroll
    for (int dq = 0; dq < 8; ++dq) {
        const int d0 = w * 32 + dq * 4;
        f32x4 q4 = *(const f32x4*)(Wk + dq * 4);
        { float xv = xe[(size_t)(d0 + 0) * TT]; float dlt = q4[0] - xv; outq[(size_t)(d0 + 0) * TT] = xv + dlt; acc = fmaf(dlt, dlt, acc); }
        { float xv = xe[(size_t)(d0 + 1) * TT]; float dlt = q4[1] - xv; outq[(size_t)(d0 + 1) * TT] = xv + dlt; acc = fmaf(dlt, dlt, acc); }
        { float xv = xe[(size_t)(d0 + 2) * TT]; float dlt = q4[2] - xv; outq[(size_t)(d0 + 2) * TT] = xv + dlt; acc = fmaf(dlt, dlt, acc); }
        { float xv = xe[(size_t)(d0 + 3) * TT]; float dlt = q4[3] - xv; outq[(size_t)(d0 + 3) * TT] = xv + dlt; acc = fmaf(dlt, dlt, acc); }
    }
    #pragma unroll
    for (int off = 32; off > 0; off >>= 1) acc += __shfl_down(acc, off, 64);
    if (lane == 0) wred[w] = acc;
    __syncthreads();
    if (tid == 0) {
        float ssum = (wred[0] + wred[1]) + (wred[2] + wred[3]);
        atomicAdd(&d_out[LOSS_IDX], ssum * (COMMIT / (float)QSIZE));
    }
}

extern "C" void kernel_launch(void* const* d_in, const int* in_sizes, int n_in,
                              void* d_out, int out_size, void* d_ws, size_t ws_size,
                              hipStream_t stream) {
    const float* x = (const float*)d_in[0];
    const float* W = (const float*)d_in[1];
    float* out = (float*)d_out;
    float* ws = (float*)d_ws;   // [0,4KB): wsq ; [4KB, 4KB+512KB): W f16 planes

    vq_prep<<<64, 256, 0, stream>>>(W, ws, out);
    vq_main<<<65536 / ROWS, TPB, 0, stream>>>(x, W, ws, out);
}